// Round 1
// baseline (148.524 us; speedup 1.0000x reference)
//
#include <hip/hip_runtime.h>

// Trilinear interpolation over a 256^3 f32 grid, one thread per point.
// Reference semantics: corners = floor/ceil per axis; weight factor per axis is
// |opposite - index| with 0 -> 1 (degenerate integer-coordinate axes); output =
// sum(v*w)/sum(w), zeroed for invalid points.

#define NX 256
#define NY 256
#define NZ 256

__global__ __launch_bounds__(256) void simplegrid_kernel(
    const float* __restrict__ x,
    const float* __restrict__ grid,
    const float* __restrict__ lower,
    const float* __restrict__ res,
    float* __restrict__ out,
    int n)
{
    int i = blockIdx.x * blockDim.x + threadIdx.x;
    if (i >= n) return;

    // lower/res are 3-element arrays; broadcast reads hit L1/L2.
    float l0 = lower[0], l1 = lower[1], l2 = lower[2];
    float r0 = res[0],   r1 = res[1],   r2 = res[2];

    float px = x[3 * i + 0];
    float py = x[3 * i + 1];
    float pz = x[3 * i + 2];

    float ix = (px - l0) / r0;
    float iy = (py - l1) / r1;
    float iz = (pz - l2) / r2;

    bool valid = (ix >= 0.0f) && (ix <= (float)(NX - 1)) &&
                 (iy >= 0.0f) && (iy <= (float)(NY - 1)) &&
                 (iz >= 0.0f) && (iz <= (float)(NZ - 1));
    if (!valid) { out[i] = 0.0f; return; }

    float flx = floorf(ix), fcx = ceilf(ix);
    float fly = floorf(iy), fcy = ceilf(iy);
    float flz = floorf(iz), fcz = ceilf(iz);

    int x0 = (int)flx, x1 = (int)fcx;
    int y0 = (int)fly, y1 = (int)fcy;
    int z0 = (int)flz, z1 = (int)fcz;

    // Weight for corner with bit set (corner at ceil, opposite is floor): |lo - idx|
    // Weight for corner with bit clear (corner at floor, opposite is ceil): |hi - idx|
    // Zero distance (integer coordinate on that axis) -> 1.
    float wsx = ix - flx; if (wsx == 0.0f) wsx = 1.0f;
    float wux = fcx - ix; if (wux == 0.0f) wux = 1.0f;
    float wsy = iy - fly; if (wsy == 0.0f) wsy = 1.0f;
    float wuy = fcy - iy; if (wuy == 0.0f) wuy = 1.0f;
    float wsz = iz - flz; if (wsz == 0.0f) wsz = 1.0f;
    float wuz = fcz - iz; if (wuz == 0.0f) wuz = 1.0f;

    // flat index = cx*NY*NZ + cy*NZ + cz
    int bx0 = x0 << 16, bx1 = x1 << 16;   // * (NY*NZ) = 65536
    int by0 = y0 << 8,  by1 = y1 << 8;    // * NZ = 256

    const float* __restrict__ g = grid;

    // corner k: bit0 -> axis0 (x), bit1 -> axis1 (y), bit2 -> axis2 (z)
    float v0 = g[bx0 + by0 + z0];  float w0 = wux * wuy * wuz;
    float v1 = g[bx1 + by0 + z0];  float w1 = wsx * wuy * wuz;
    float v2 = g[bx0 + by1 + z0];  float w2 = wux * wsy * wuz;
    float v3 = g[bx1 + by1 + z0];  float w3 = wsx * wsy * wuz;
    float v4 = g[bx0 + by0 + z1];  float w4 = wux * wuy * wsz;
    float v5 = g[bx1 + by0 + z1];  float w5 = wsx * wuy * wsz;
    float v6 = g[bx0 + by1 + z1];  float w6 = wux * wsy * wsz;
    float v7 = g[bx1 + by1 + z1];  float w7 = wsx * wsy * wsz;

    float num = v0 * w0 + v1 * w1 + v2 * w2 + v3 * w3 +
                v4 * w4 + v5 * w5 + v6 * w6 + v7 * w7;
    float den = w0 + w1 + w2 + w3 + w4 + w5 + w6 + w7;

    out[i] = num / den;
}

extern "C" void kernel_launch(void* const* d_in, const int* in_sizes, int n_in,
                              void* d_out, int out_size, void* d_ws, size_t ws_size,
                              hipStream_t stream) {
    const float* x     = (const float*)d_in[0];
    const float* grid  = (const float*)d_in[1];
    const float* lower = (const float*)d_in[2];
    const float* res   = (const float*)d_in[3];
    float* out = (float*)d_out;

    int n = in_sizes[0] / 3;  // x is [N,3]
    int block = 256;
    int blocks = (n + block - 1) / block;
    simplegrid_kernel<<<blocks, block, 0, stream>>>(x, grid, lower, res, out, n);
}